// Round 9
// baseline (208.911 us; speedup 1.0000x reference)
//
#include <hip/hip_runtime.h>
#include <math.h>

// Problem constants (setup_inputs: S=2048, U=10, D=256)
#define SS   2048
#define UU   10
#define DD   256
#define BB   (SS * UU)   // 20480 rows
#define EPSF 1e-8f

typedef __attribute__((ext_vector_type(8))) short   bf16x8;
typedef __attribute__((ext_vector_type(4))) float   floatx4;

__device__ static inline unsigned short f2bf(float f) {
    union { float f; unsigned u; } v; v.f = f;
    unsigned r = (v.u + 0x7FFFu + ((v.u >> 16) & 1u)) >> 16;  // RNE
    return (unsigned short)r;
}

__device__ static inline void gl_lds16(const unsigned short* g, unsigned short* l) {
    // 16B per lane; LDS dest = wave-uniform base + lane*16
    __builtin_amdgcn_global_load_lds((const __attribute__((address_space(1))) void*)g,
                                     (__attribute__((address_space(3))) void*)l, 16, 0, 0);
}

// ---- Kernel 1: barrier-free prep (r7, proven) + zero cnt/out/sumexp ----
#define NORM_NBLK (BB / 4)   // 5120
#define CENT_NBLK (SS / 4)   // 512
#define NBM       320        // BB / 64 row-groups

__global__ __launch_bounds__(256) void prep_kernel(const float* __restrict__ E,
                                                   unsigned short* __restrict__ Enb,
                                                   unsigned short* __restrict__ Cnb,
                                                   float* __restrict__ sumexp,
                                                   int* __restrict__ cnt,
                                                   float* __restrict__ out) {
    const int wid = threadIdx.x >> 6, lane = threadIdx.x & 63;
    const int b = blockIdx.x;

    if (b < NORM_NBLK) {
        if (b < NBM && threadIdx.x == 0) cnt[b] = 0;
        const int row = b * 4 + wid;
        const float4 v = ((const float4*)(E + (size_t)row * DD))[lane];
        float ssq = v.x * v.x + v.y * v.y + v.z * v.z + v.w * v.w;
#pragma unroll
        for (int off = 32; off; off >>= 1) ssq += __shfl_xor(ssq, off, 64);
        const float rinv = 1.0f / fmaxf(sqrtf(ssq), EPSF);
        ushort4 o;
        o.x = f2bf(v.x * rinv); o.y = f2bf(v.y * rinv);
        o.z = f2bf(v.z * rinv); o.w = f2bf(v.w * rinv);
        ((ushort4*)(Enb + (size_t)row * DD))[lane] = o;
        if (lane == 0) {
            sumexp[row] = 0.f;
            if (row == 0) out[0] = 0.f;
        }
    } else {
        const int s = (b - NORM_NBLK) * 4 + wid;
        const float* base = E + (size_t)s * UU * DD + lane * 4;
        float4 c = {0.f, 0.f, 0.f, 0.f};
#pragma unroll
        for (int u = 0; u < UU; ++u) {
            const float4 v = *(const float4*)(base + u * DD);
            c.x += v.x; c.y += v.y; c.z += v.z; c.w += v.w;
        }
        c.x *= 0.1f; c.y *= 0.1f; c.z *= 0.1f; c.w *= 0.1f;
        float ssq = c.x * c.x + c.y * c.y + c.z * c.z + c.w * c.w;
#pragma unroll
        for (int off = 32; off; off >>= 1) ssq += __shfl_xor(ssq, off, 64);
        const float rinv = 1.0f / fmaxf(sqrtf(ssq), EPSF);
        ushort4 o;
        o.x = f2bf(c.x * rinv); o.y = f2bf(c.y * rinv);
        o.z = f2bf(c.z * rinv); o.w = f2bf(c.w * rinv);
        ((ushort4*)(Cnb + (size_t)s * DD))[lane] = o;
    }
}

// ---- Kernel 2: barrier-free streaming GEMM + exp-sum + pos + fused finalize ----
// Block: 64 rows x 512 cols. A (64x256=32KB) LDS-resident, staged once (1 barrier).
// Each wave: private 128 cols as 2 chunks x 8 k-stages; B in per-wave 3-deep ring
// (4KB/stage) via global_load_lds, prefetch distance 2, s_waitcnt vmcnt(8) guard.
// No __syncthreads in the whole K-loop. Last of 16 waves per bm finalizes.
__global__ __launch_bounds__(256, 2) void gemm_lse_kernel(const unsigned short* __restrict__ Enb,
                                                          const unsigned short* __restrict__ Cnb,
                                                          float* __restrict__ posArr,
                                                          float* __restrict__ sumexp,
                                                          int* __restrict__ cnt,
                                                          float* __restrict__ out) {
    __shared__ unsigned short As[64 * 256];      // 32 KB, granule slot = g ^ (row&7)
    __shared__ unsigned short Bs[4][3][2048];    // 48 KB: per-wave 3-stage ring

    const int tid  = threadIdx.x;
    const int wid  = tid >> 6, lane = tid & 63;
    const int l15  = lane & 15, quad = lane >> 4;

    const int q  = blockIdx.x & 3;               // n-quarter
    const int bm = blockIdx.x >> 2;              // 0..319
    const int row0 = bm * 64;
    const int c0   = q * 512 + wid * 128;        // this wave's 128-col base

    // ---- stage A once: 32 chunks of 2 rows x 256k (1 KB each), 8 per wave.
    {
        const int rl2 = lane >> 5;               // 0/1
        const int sl2 = lane & 31;               // granule slot 0..31
#pragma unroll
        for (int i = 0; i < 8; ++i) {
            const int ci  = wid * 8 + i;
            const int row = ci * 2 + rl2;
            const int g   = sl2 ^ (row & 7);     // logical granule to fetch
            gl_lds16(Enb + (size_t)(row0 + row) * DD + g * 8, As + ci * 512);
        }
    }

    // ---- pre-issue B stages 0,1 (drained by the barrier below)
    const int rl = lane >> 2;                    // col-within-16 0..15
    const int gfb = ((lane & 3) ^ ((rl >> 1) & 3)) * 8;
#pragma unroll
    for (int t = 0; t < 2; ++t) {
#pragma unroll
        for (int i = 0; i < 4; ++i) {
            const int colg = c0 + (t >> 3) * 64 + i * 16 + rl;
            gl_lds16(Cnb + (size_t)colg * DD + (t & 7) * 32 + gfb,
                     &Bs[wid][t % 3][i * 512]);
        }
    }

    __syncthreads();   // the only barrier: As resident, B stages 0,1 landed

    const int bswz = (quad ^ ((l15 >> 1) & 3)) * 8;
    const int aswz = quad ^ (l15 & 7);           // granule XOR key for A reads
    int arow[4];
#pragma unroll
    for (int mt = 0; mt < 4; ++mt) arow[mt] = (mt * 16 + l15) * 256;

    floatx4 acc[4][4];
#pragma unroll
    for (int i = 0; i < 4; ++i)
#pragma unroll
        for (int j = 0; j < 4; ++j) acc[i][j] = (floatx4){0.f, 0.f, 0.f, 0.f};

#pragma unroll
    for (int s = 0; s < 16; ++s) {               // 2 chunks x 8 k-stages
        // prefetch stage s+2
        if (s < 14) {
            const int t = s + 2;
#pragma unroll
            for (int i = 0; i < 4; ++i) {
                const int colg = c0 + (t >> 3) * 64 + i * 16 + rl;
                gl_lds16(Cnb + (size_t)colg * DD + (t & 7) * 32 + gfb,
                         &Bs[wid][t % 3][i * 512]);
            }
            asm volatile("s_waitcnt vmcnt(8)" ::: "memory");
        } else if (s == 14) {
            asm volatile("s_waitcnt vmcnt(4)" ::: "memory");
        } else {
            asm volatile("s_waitcnt vmcnt(0)" ::: "memory");
        }

        const int ks = s & 7;
        bf16x8 af[4], bfr[4];
#pragma unroll
        for (int mt = 0; mt < 4; ++mt)
            af[mt] = *(const bf16x8*)(As + arow[mt] + ((ks * 4) ^ aswz) * 8
                                      + (((ks * 4) ^ aswz) >= ((ks * 4 + quad) ^ aswz) ? 0 : 0));
#pragma unroll
        for (int mt = 0; mt < 4; ++mt)
            af[mt] = *(const bf16x8*)(As + arow[mt] + (((ks * 4 + quad) ^ (l15 & 7)) * 8));
#pragma unroll
        for (int nt = 0; nt < 4; ++nt)
            bfr[nt] = *(const bf16x8*)(&Bs[wid][s % 3][(nt * 16 + l15) * 32 + bswz]);
#pragma unroll
        for (int mt = 0; mt < 4; ++mt)
#pragma unroll
            for (int nt = 0; nt < 4; ++nt)
                acc[mt][nt] = __builtin_amdgcn_mfma_f32_16x16x32_bf16(af[mt], bfr[nt], acc[mt][nt], 0, 0, 0);

        // chunk epilogue after stages 7 and 15
        if (ks == 7) {
            const int cbase = c0 + (s >> 3) * 64;
#pragma unroll
            for (int mt = 0; mt < 4; ++mt) {
                float rs[4] = {0.f, 0.f, 0.f, 0.f};
                const int growb = row0 + mt * 16 + quad * 4;
#pragma unroll
                for (int nt = 0; nt < 4; ++nt) {
                    const int col = cbase + nt * 16 + l15;
#pragma unroll
                    for (int r = 0; r < 4; ++r) {
                        const int grow = growb + r;
                        const float sim = acc[mt][nt][r];
                        if (col == grow / UU) {
                            posArr[grow] = sim;   // excluded from sum (-inf mask)
                        } else {
                            rs[r] += __expf(sim);
                        }
                        acc[mt][nt][r] = 0.f;     // reset for next chunk
                    }
                }
#pragma unroll
                for (int m = 1; m < 16; m <<= 1) {
#pragma unroll
                    for (int r = 0; r < 4; ++r) rs[r] += __shfl_xor(rs[r], m, 64);
                }
                if (l15 == 0) {
#pragma unroll
                    for (int r = 0; r < 4; ++r) atomicAdd(&sumexp[growb + r], rs[r]);
                }
            }
        }
    }

    // ---- fused finalize: last of the 16 waves covering this bm does the rows
    __threadfence();
    int old = 0;
    if (lane == 0) old = atomicAdd(&cnt[bm], 1);
    old = __shfl(old, 0, 64);
    if (old == 15) {
        __threadfence();
        const float se = atomicAdd(&sumexp[row0 + lane], 0.0f);   // coherent fetch
        const float ps = atomicAdd(&posArr[row0 + lane], 0.0f);
        float t = __logf(se) - ps;
#pragma unroll
        for (int off = 32; off; off >>= 1) t += __shfl_xor(t, off, 64);
        if (lane == 0) atomicAdd(out, t * (1.0f / (float)BB));
    }
}

extern "C" void kernel_launch(void* const* d_in, const int* in_sizes, int n_in,
                              void* d_out, int out_size, void* d_ws, size_t ws_size,
                              hipStream_t stream) {
    const float* E = (const float*)d_in[0];
    float* out = (float*)d_out;

    unsigned short* Enb = (unsigned short*)d_ws;            // BB*DD bf16 = 10.5 MB
    unsigned short* Cnb = Enb + (size_t)BB * DD;            // SS*DD bf16 = 1 MB
    float* posArr = (float*)(Cnb + (size_t)SS * DD);        // BB floats
    float* sumexp = posArr + BB;                            // BB floats (zeroed by prep)
    int*   cnt    = (int*)(sumexp + BB);                    // NBM ints (zeroed by prep)

    prep_kernel<<<NORM_NBLK + CENT_NBLK, 256, 0, stream>>>(E, Enb, Cnb, sumexp, cnt, out);
    gemm_lse_kernel<<<NBM * 4, 256, 0, stream>>>(Enb, Cnb, posArr, sumexp, cnt, out);
}